// Round 10
// baseline (42348.535 us; speedup 1.0000x reference)
//
#include <hip/hip_runtime.h>
#include <hip/hip_bf16.h>
#include <math.h>

#define B_   64
#define T_   256
#define DIN_ 512
#define H_   512
#define D_   1024
#define O_   1536
#define TB_  (T_*B_)
#define EPSf 1e-5f
#define NWG  96          // persistent WGs; WG w owns y-cols [16w,16w+16)
#define NSLOT (T_ + 6)   // wavefront slots: t = s - 2l

typedef short  bf16x8 __attribute__((ext_vector_type(8)));
typedef float  f32x4  __attribute__((ext_vector_type(4)));
typedef ushort u16x4  __attribute__((ext_vector_type(4)));

#define SPLIT1(f, Hm, Lm) { __hip_bfloat16 _h = __float2bfloat16(f); (Hm) = *(ushort*)&_h; \
    __hip_bfloat16 _l = __float2bfloat16((f) - __bfloat162float(_h)); (Lm) = *(ushort*)&_l; }

__device__ inline void st_f32_coh(float* p, float v) {
    __hip_atomic_store(p, v, __ATOMIC_RELAXED, __HIP_MEMORY_SCOPE_AGENT);
}
__device__ inline void st_u16_coh(ushort* p, ushort v) {
    __hip_atomic_store(p, v, __ATOMIC_RELAXED, __HIP_MEMORY_SCOPE_AGENT);
}
__device__ inline void st_f32x2_coh(float* p, float a, float b) {
    union { float f[2]; unsigned long long u; } pk;
    pk.f[0] = a; pk.f[1] = b;
    __hip_atomic_store((unsigned long long*)p, pk.u, __ATOMIC_RELAXED,
                       __HIP_MEMORY_SCOPE_AGENT);
}
__device__ inline void at_add_coh(float* p, float v) {
    (void)__hip_atomic_fetch_add(p, v, __ATOMIC_RELAXED, __HIP_MEMORY_SCOPE_AGENT);
}

// ---------------- mask codes: mcode[t*B+b] = mt | (mn<<1) ----------------
__global__ __launch_bounds__(256) void k_mask(const int* __restrict__ mask,
                                              int* __restrict__ mcode) {
    int g = blockIdx.x * 256 + threadIdx.x;
    int t = g >> 6, b = g & 63;
    int mt = mask[b * T_ + t] != 0;
    int mn = (t + 1 < T_) ? (mask[b * T_ + t + 1] != 0) : 0;
    mcode[g] = mt | (mn << 1);
}

// ---- x split: Xb0[t*64+b][k] = split(k<512 ? x[b][t][k] : 0) ----
__global__ __launch_bounds__(256) void k_prepx(const float* __restrict__ x,
                                               ushort* __restrict__ Xh,
                                               ushort* __restrict__ Xl) {
    int g  = blockIdx.x * 256 + threadIdx.x;
    int i4 = g * 4;
    int row = i4 >> 10;
    int k   = i4 & 1023;
    int t = row >> 6, b = row & 63;
    float4 v = make_float4(0.f, 0.f, 0.f, 0.f);
    if (k < 512) v = *(const float4*)&x[((size_t)b * T_ + t) * 512 + k];
    u16x4 h, l;
    SPLIT1(v.x, h[0], l[0]); SPLIT1(v.y, h[1], l[1]);
    SPLIT1(v.z, h[2], l[2]); SPLIT1(v.w, h[3], l[3]);
    *(u16x4*)&Xh[i4] = h;
    *(u16x4*)&Xl[i4] = l;
}

// ---- transpose + split-bf16: Mt_hi[o][k]+Mt_lo[o][k] ≈ M[k][o]  (M is [D_][O_]) ----
__global__ __launch_bounds__(256) void k_prep(const float* __restrict__ M,
                                              ushort* __restrict__ Mt_hi,
                                              ushort* __restrict__ Mt_lo) {
    __shared__ float ls[64][65];
    int k0 = blockIdx.y * 64;
    int o0 = blockIdx.x * 64;
    int tid = threadIdx.x;
    int r = tid >> 2, cq = tid & 3;
#pragma unroll
    for (int j = 0; j < 4; ++j) {
        float4 v = *(const float4*)&M[(size_t)(k0 + r) * O_ + o0 + cq * 16 + j * 4];
        ls[r][cq * 16 + j * 4 + 0] = v.x;
        ls[r][cq * 16 + j * 4 + 1] = v.y;
        ls[r][cq * 16 + j * 4 + 2] = v.z;
        ls[r][cq * 16 + j * 4 + 3] = v.w;
    }
    __syncthreads();
    int ol = tid >> 2, kq = tid & 3;
    ushort th[16], tl[16];
#pragma unroll
    for (int j = 0; j < 16; ++j) {
        float v = ls[kq * 16 + j][ol];
        SPLIT1(v, th[j], tl[j]);
    }
    size_t base = (size_t)(o0 + ol) * D_ + k0 + kq * 16;
    *(int4*)&Mt_hi[base]     = *(int4*)&th[0];
    *(int4*)&Mt_hi[base + 8] = *(int4*)&th[8];
    *(int4*)&Mt_lo[base]     = *(int4*)&tl[0];
    *(int4*)&Mt_lo[base + 8] = *(int4*)&tl[8];
}

// ------ barrier: sc1-store protocol (verified round 8) ------
__device__ inline void gbar(unsigned* __restrict__ fl, int w, unsigned bar) {
    __syncthreads();
    asm volatile("s_waitcnt vmcnt(0)" ::: "memory");
    if (threadIdx.x == 0)
        __hip_atomic_store(&fl[w], bar, __ATOMIC_RELAXED, __HIP_MEMORY_SCOPE_AGENT);
    if (threadIdx.x < NWG) {
        while (__hip_atomic_load(&fl[threadIdx.x], __ATOMIC_RELAXED,
                                 __HIP_MEMORY_SCOPE_AGENT) < bar)
            __builtin_amdgcn_s_sleep(2);
    }
    __syncthreads();
    __builtin_amdgcn_fence(__ATOMIC_ACQUIRE, "agent");
}

// ================= 4-layer wavefront pipeline =================
// 96 WGs; WG w owns cols [16w,16w+16). wave wv owns rows [16wv,16wv+16).
// slot s: layer l does step t = s-2l. 2 barriers per slot.
__global__ __launch_bounds__(256, 1) void k_pipe(
        const float* __restrict__ x,
        const ushort* __restrict__ Xbh, const ushort* __restrict__ Xbl,
        ushort* __restrict__ Xrh, ushort* __restrict__ Xrl,
        ushort* __restrict__ Hbh, ushort* __restrict__ Hbl,
        float* __restrict__ Y1, float* __restrict__ Y2,
        float* __restrict__ stats, unsigned* __restrict__ flags,
        const ushort* __restrict__ Uth, const ushort* __restrict__ Utl,
        const ushort* __restrict__ Wth, const ushort* __restrict__ Wtl,
        const float* __restrict__ gam, const float* __restrict__ bet,
        const float* __restrict__ bias,
        const int* __restrict__ mcode, float* __restrict__ out) {
    __shared__ __hip_bfloat16 lds[4 * 16 * 1024];   // [U_hi|U_lo|W_hi|W_lo] 32KB each
    const int w = blockIdx.x;
    const int tid = threadIdx.x;
    const int lane = tid & 63;
    const int wv = tid >> 6;
    const int lr = lane & 15;
    const int lg = lane >> 4;
    const int c0 = w * 16;
    const int b0 = wv * 16;

    // stage U/W tiles (cols c0..c0+16) into LDS, XOR-swizzled
    {
        int cl = tid >> 4, kc = tid & 15;
        const ushort* srcs0 = Uth + (size_t)(c0 + cl) * D_ + kc * 64;
        const ushort* srcs1 = Utl + (size_t)(c0 + cl) * D_ + kc * 64;
        const ushort* srcs2 = Wth + (size_t)(c0 + cl) * D_ + kc * 64;
        const ushort* srcs3 = Wtl + (size_t)(c0 + cl) * D_ + kc * 64;
        char* base = (char*)lds;
#pragma unroll
        for (int j = 0; j < 8; ++j) {
            int k = kc * 64 + j * 8;
            int off = (cl * 2048 + k * 2) ^ ((cl & 7) << 4);
            *(int4*)(base + off)           = *(const int4*)(srcs0 + j * 8);
            *(int4*)(base + 32768 + off)   = *(const int4*)(srcs1 + j * 8);
            *(int4*)(base + 65536 + off)   = *(const int4*)(srcs2 + j * 8);
            *(int4*)(base + 98304 + off)   = *(const int4*)(srcs3 + j * 8);
        }
    }
    __syncthreads();

    const int d = c0 + lr;
    const bool gate_w = (w < 64);
    const bool tanh_w = (w >= 32 && w < 64);
    float g0d = 0.f, g1d = 0.f, cd = 0.f, g0e = 0.f, g1e = 0.f, ce = 0.f;
    if (gate_w) {
        g0d = gam[d]; g1d = gam[O_ + d];
        cd  = bet[d] + bet[O_ + d] + bias[d];
    }
    if (tanh_w) {
        int e = d + 512;
        g0e = gam[e]; g1e = gam[O_ + e];
        ce  = bet[e] + bet[O_ + e] + bias[e];
    }
    int brow[4];
#pragma unroll
    for (int j = 0; j < 4; ++j) brow[j] = b0 + lg * 4 + j;

    // per-layer per-row register state (gate waves)
    float h1r[4][4] = {}, fk1r[4][4] = {};
    float oh_d1[4][4] = {}, oh_d2[4][4] = {}, fkp_d1[4][4] = {};
    f32x4 acc1[4], acc2[4];

    unsigned bar = 0;
    for (int s = 0; s < NSLOT; ++s) {
        const int par = s & 1;
        // ---------------- phase 1 ----------------
        // zero next-parity stats (row w, all layers)
        if (gate_w && tid == 0) {
#pragma unroll
            for (int l = 0; l < 4; ++l) {
                float* zp = &stats[(((size_t)(par ^ 1) * 4 + l) * 64 + w) * 4];
                st_f32x2_coh(zp, 0.f, 0.f);
                st_f32x2_coh(zp + 2, 0.f, 0.f);
            }
        }
#pragma unroll
        for (int l = 0; l < 4; ++l) {
            int t = s - 2 * l;
            bool act = (t >= 0) && (t < T_);
            if (!act) continue;
            const ushort* xsh;
            const ushort* xsl;
            if (l == 0) {
                xsh = Xbh + ((size_t)t * B_ + b0 + lr) * D_;
                xsl = Xbl + ((size_t)t * B_ + b0 + lr) * D_;
            } else {
                size_t rb = (((size_t)l * 3 + (t % 3)) * B_ + b0 + lr) * D_;
                xsh = Xrh + rb;
                xsl = Xrl + rb;
            }
            const ushort* hsh = Hbh + ((size_t)l * B_ + b0 + lr) * D_;
            const ushort* hsl = Hbl + ((size_t)l * B_ + b0 + lr) * D_;
            const char* lb = (const char*)lds;
            f32x4 a10 = {0,0,0,0}, a11 = {0,0,0,0}, a12 = {0,0,0,0};
            f32x4 a20 = {0,0,0,0}, a21 = {0,0,0,0}, a22 = {0,0,0,0};
#pragma unroll 8
            for (int kc = 0; kc < 32; ++kc) {
                int k = kc * 32 + lg * 8;
                int off = (lr * 2048 + k * 2) ^ ((lr & 7) << 4);
                bf16x8 xah = *(const bf16x8*)(xsh + k);
                bf16x8 xal = *(const bf16x8*)(xsl + k);
                bf16x8 hah = *(const bf16x8*)(hsh + k);
                bf16x8 hal = *(const bf16x8*)(hsl + k);
                bf16x8 ubh = *(const bf16x8*)(lb + off);
                bf16x8 ubl = *(const bf16x8*)(lb + 32768 + off);
                bf16x8 wbh = *(const bf16x8*)(lb + 65536 + off);
                bf16x8 wbl = *(const bf16x8*)(lb + 98304 + off);
                a10 = __builtin_amdgcn_mfma_f32_16x16x32_bf16(xah, wbh, a10, 0, 0, 0);
                a11 = __builtin_amdgcn_mfma_f32_16x16x32_bf16(xah, wbl, a11, 0, 0, 0);
                a12 = __builtin_amdgcn_mfma_f32_16x16x32_bf16(xal, wbh, a12, 0, 0, 0);
                a20 = __builtin_amdgcn_mfma_f32_16x16x32_bf16(hah, ubh, a20, 0, 0, 0);
                a21 = __builtin_amdgcn_mfma_f32_16x16x32_bf16(hah, ubl, a21, 0, 0, 0);
                a22 = __builtin_amdgcn_mfma_f32_16x16x32_bf16(hal, ubh, a22, 0, 0, 0);
            }
            acc1[l] = a10 + a11 + a12;
            acc2[l] = a20 + a21 + a22;
            // stats partials -> atomic accumulate (parity par)
#pragma unroll
            for (int j = 0; j < 4; ++j) {
                float s1 = acc1[l][j], q1 = s1 * s1;
                float s2 = acc2[l][j], q2 = s2 * s2;
#pragma unroll
                for (int m = 1; m < 16; m <<= 1) {
                    s1 += __shfl_xor(s1, m); q1 += __shfl_xor(q1, m);
                    s2 += __shfl_xor(s2, m); q2 += __shfl_xor(q2, m);
                }
                if (lr == 0) {
                    float* sp = &stats[(((size_t)par * 4 + l) * 64 + brow[j]) * 4];
                    at_add_coh(sp + 0, s1);
                    at_add_coh(sp + 1, q1);
                    at_add_coh(sp + 2, s2);
                    at_add_coh(sp + 3, q2);
                }
            }
            // export tanh-partner cols (w>=64)
            if (w >= 64) {
                int cexp = c0 + lr - 1024;
#pragma unroll
                for (int j = 0; j < 4; ++j) {
                    st_f32_coh(&Y1[((size_t)l * B_ + brow[j]) * 512 + cexp], acc1[l][j]);
                    st_f32_coh(&Y2[((size_t)l * B_ + brow[j]) * 512 + cexp], acc2[l][j]);
                }
            }
        }
        gbar(flags, w, ++bar);

        // ---------------- phase 2: gating (descending layers) ----------------
        if (gate_w) {
#pragma unroll
            for (int li = 0; li < 4; ++li) {
                const int l = 3 - li;
                const int lp = (l > 0) ? l - 1 : 0;   // safe static index
                int t = s - 2 * l;
                bool act = (t >= 0) && (t < T_);
                float ohn[4], ofkn[4];
                if (act) {
                    int4 mc4 = *(const int4*)&mcode[t * B_ + b0 + lg * 4];
                    int mcarr[4] = {mc4.x, mc4.y, mc4.z, mc4.w};
#pragma unroll
                    for (int j = 0; j < 4; ++j) {
                        int b = brow[j];
                        float4 sv = *(const float4*)
                            &stats[(((size_t)par * 4 + l) * 64 + b) * 4];
                        float m1 = sv.x * (1.f / O_);
                        float v1 = sv.y * (1.f / O_) - m1 * m1;
                        float i1 = 1.f / (sqrtf(v1 + EPSf) + EPSf);
                        float m2 = sv.z * (1.f / O_);
                        float v2 = sv.w * (1.f / O_) - m2 * m2;
                        float i2 = 1.f / (sqrtf(v2 + EPSf) + EPSf);
                        float y1 = acc1[l][j], y2 = acc2[l][j];
                        float td = g0d * (y1 - m1) * i1 + g1d * (y2 - m2) * i2 + cd;
                        float fkc = fminf(fmaxf(0.2f * td + 0.5f, 0.f), 1.f);
                        float hpad = 0.f;
                        if (tanh_w) {
                            float y1e = Y1[((size_t)l * B_ + b) * 512 + (d - 512)];
                            float y2e = Y2[((size_t)l * B_ + b) * 512 + (d - 512)];
                            float te = g0e * (y1e - m1) * i1 + g1e * (y2e - m2) * i2 + ce;
                            hpad = tanhf(te);
                        }
                        float xt;
                        if (l == 0)
                            xt = (d < 512) ? x[((size_t)b * T_ + t) * 512 + d] : 0.f;
                        else
                            xt = oh_d2[lp][j];
                        float fkp = (l > 0 && t + 1 < T_) ? fkp_d1[lp][j] : 0.f;
                        float hc = (1.f - fkc) * xt + fkc * hpad;
                        float h  = fkp * h1r[l][j] + (1.f - fkp) * hc;
                        float fk = fkp + (1.f - fkp) * fkc;
                        int mt = mcarr[j] & 1, mn = (mcarr[j] >> 1) & 1;
                        if (mt && !mn) fk = 0.f;
                        float oh  = mt ? h  : h1r[l][j];
                        float ofk = mt ? fk : fk1r[l][j];
                        h1r[l][j] = oh; fk1r[l][j] = ofk;
                        // state exports (sc1): Hb for (l,t+1) matvec; Xr for layer l+1
                        ushort hi, lo;
                        SPLIT1(oh, hi, lo);
                        st_u16_coh(Hbh + ((size_t)l * B_ + b) * D_ + d, hi);
                        st_u16_coh(Hbl + ((size_t)l * B_ + b) * D_ + d, lo);
                        if (l < 3) {
                            size_t xb = (((size_t)(l + 1) * 3 + (t % 3)) * B_ + b) * D_ + d;
                            st_u16_coh(Xrh + xb, hi);
                            st_u16_coh(Xrl + xb, lo);
                        }
                        if (l == 3 && t == T_ - 1 && d >= 512)
                            out[(size_t)b * 512 + (d - 512)] = oh;
                        ohn[j] = oh; ofkn[j] = ofk;
                    }
                }
                // delay-line shift (always shift d2<-d1; update d1 only if active)
#pragma unroll
                for (int j = 0; j < 4; ++j) {
                    oh_d2[l][j] = oh_d1[l][j];
                    if (act) { oh_d1[l][j] = ohn[j]; fkp_d1[l][j] = ofkn[j]; }
                }
            }
        }
        gbar(flags, w, ++bar);
    }
}

extern "C" void kernel_launch(void* const* d_in, const int* in_sizes, int n_in,
                              void* d_out, int out_size, void* d_ws, size_t ws_size,
                              hipStream_t stream) {
    (void)in_sizes; (void)n_in; (void)out_size;
    const float* x      = (const float*)d_in[0];
    const int*   mask   = (const int*)d_in[1];
    const float* W      = (const float*)d_in[2];
    const float* U      = (const float*)d_in[3];
    const float* bias   = (const float*)d_in[4];
    const float* gammas = (const float*)d_in[5];
    const float* betas  = (const float*)d_in[6];

    float* ws = (float*)d_ws;
    float* Y1    = ws;                                   // 4*B_*512
    float* Y2    = Y1 + (size_t)4 * B_ * 512;            // 4*B_*512
    float* stats = Y2 + (size_t)4 * B_ * 512;            // 2*4*64*4
    unsigned* flags = (unsigned*)(stats + 2 * 4 * 64 * 4);   // 128
    int* mcode = (int*)(flags + 128);                    // TB_
    ushort* Xbh = (ushort*)(mcode + TB_);                // TB_*D_
    ushort* Xbl = Xbh + (size_t)TB_ * D_;                // TB_*D_
    ushort* Xrh = Xbl + (size_t)TB_ * D_;                // 4*3*B_*D_
    ushort* Xrl = Xrh + (size_t)4 * 3 * B_ * D_;
    ushort* Hbh = Xrl + (size_t)4 * 3 * B_ * D_;         // 4*B_*D_
    ushort* Hbl = Hbh + (size_t)4 * B_ * D_;             // 4*B_*D_
    ushort* Uth = Hbl + (size_t)4 * B_ * D_;             // O_*D_
    ushort* Utl = Uth + (size_t)O_ * D_;
    ushort* Wth = Utl + (size_t)O_ * D_;
    ushort* Wtl = Wth + (size_t)O_ * D_;
    size_t need_bytes = ((char*)(Wtl + (size_t)O_ * D_)) - ((char*)d_ws);
    if (ws_size < need_bytes) return;

    k_prepx<<<TB_ * D_ / 4 / 256, 256, 0, stream>>>(x, Xbh, Xbl);
    k_mask<<<TB_ / 256, 256, 0, stream>>>(mask, mcode);
    k_prep<<<dim3(O_ / 64, D_ / 64), 256, 0, stream>>>(U, Uth, Utl);
    k_prep<<<dim3(O_ / 64, D_ / 64), 256, 0, stream>>>(W, Wth, Wtl);
    (void)hipMemsetAsync(Hbh, 0, sizeof(ushort) * (size_t)4 * B_ * D_ * 2, stream);
    (void)hipMemsetAsync(stats, 0, sizeof(float) * 2 * 4 * 64 * 4, stream);
    (void)hipMemsetAsync(flags, 0, sizeof(unsigned) * 128, stream);

    k_pipe<<<NWG, 256, 0, stream>>>(x, Xbh, Xbl, Xrh, Xrl, Hbh, Hbl,
                                    Y1, Y2, stats, flags,
                                    Uth, Utl, Wth, Wtl,
                                    gammas, betas, bias, mcode, (float*)d_out);
}

// Round 11
// 23228.854 us; speedup vs baseline: 1.8231x; 1.8231x over previous
//
#include <hip/hip_runtime.h>
#include <hip/hip_bf16.h>
#include <math.h>

#define B_   64
#define T_   256
#define DIN_ 512
#define H_   512
#define D_   1024
#define O_   1536
#define TB_  (T_*B_)
#define EPSf 1e-5f
#define NWG  96          // persistent WGs; WG w owns y-cols [16w,16w+16)
#define NSLOT (T_ + 6)   // wavefront slots: t = s - 2l

typedef short  bf16x8 __attribute__((ext_vector_type(8)));
typedef float  f32x4  __attribute__((ext_vector_type(4)));
typedef ushort u16x4  __attribute__((ext_vector_type(4)));

#define SPLIT1(f, Hm, Lm) { __hip_bfloat16 _h = __float2bfloat16(f); (Hm) = *(ushort*)&_h; \
    __hip_bfloat16 _l = __float2bfloat16((f) - __bfloat162float(_h)); (Lm) = *(ushort*)&_l; }

__device__ inline void st_f32_coh(float* p, float v) {
    __hip_atomic_store(p, v, __ATOMIC_RELAXED, __HIP_MEMORY_SCOPE_AGENT);
}
__device__ inline void st_u16_coh(ushort* p, ushort v) {
    __hip_atomic_store(p, v, __ATOMIC_RELAXED, __HIP_MEMORY_SCOPE_AGENT);
}
__device__ inline void st_f32x2_coh(float* p, float a, float b) {
    union { float f[2]; unsigned long long u; } pk;
    pk.f[0] = a; pk.f[1] = b;
    __hip_atomic_store((unsigned long long*)p, pk.u, __ATOMIC_RELAXED,
                       __HIP_MEMORY_SCOPE_AGENT);
}

// ---------------- mask codes: mcode[t*B+b] = mt | (mn<<1) ----------------
__global__ __launch_bounds__(256) void k_mask(const int* __restrict__ mask,
                                              int* __restrict__ mcode) {
    int g = blockIdx.x * 256 + threadIdx.x;
    int t = g >> 6, b = g & 63;
    int mt = mask[b * T_ + t] != 0;
    int mn = (t + 1 < T_) ? (mask[b * T_ + t + 1] != 0) : 0;
    mcode[g] = mt | (mn << 1);
}

// ---- x split: Xb0[t*64+b][k] = split(k<512 ? x[b][t][k] : 0) ----
__global__ __launch_bounds__(256) void k_prepx(const float* __restrict__ x,
                                               ushort* __restrict__ Xh,
                                               ushort* __restrict__ Xl) {
    int g  = blockIdx.x * 256 + threadIdx.x;
    int i4 = g * 4;
    int row = i4 >> 10;
    int k   = i4 & 1023;
    int t = row >> 6, b = row & 63;
    float4 v = make_float4(0.f, 0.f, 0.f, 0.f);
    if (k < 512) v = *(const float4*)&x[((size_t)b * T_ + t) * 512 + k];
    u16x4 h, l;
    SPLIT1(v.x, h[0], l[0]); SPLIT1(v.y, h[1], l[1]);
    SPLIT1(v.z, h[2], l[2]); SPLIT1(v.w, h[3], l[3]);
    *(u16x4*)&Xh[i4] = h;
    *(u16x4*)&Xl[i4] = l;
}

// ---- transpose + split-bf16: Mt_hi[o][k]+Mt_lo[o][k] ≈ M[k][o]  (M is [D_][O_]) ----
__global__ __launch_bounds__(256) void k_prep(const float* __restrict__ M,
                                              ushort* __restrict__ Mt_hi,
                                              ushort* __restrict__ Mt_lo) {
    __shared__ float ls[64][65];
    int k0 = blockIdx.y * 64;
    int o0 = blockIdx.x * 64;
    int tid = threadIdx.x;
    int r = tid >> 2, cq = tid & 3;
#pragma unroll
    for (int j = 0; j < 4; ++j) {
        float4 v = *(const float4*)&M[(size_t)(k0 + r) * O_ + o0 + cq * 16 + j * 4];
        ls[r][cq * 16 + j * 4 + 0] = v.x;
        ls[r][cq * 16 + j * 4 + 1] = v.y;
        ls[r][cq * 16 + j * 4 + 2] = v.z;
        ls[r][cq * 16 + j * 4 + 3] = v.w;
    }
    __syncthreads();
    int ol = tid >> 2, kq = tid & 3;
    ushort th[16], tl[16];
#pragma unroll
    for (int j = 0; j < 16; ++j) {
        float v = ls[kq * 16 + j][ol];
        SPLIT1(v, th[j], tl[j]);
    }
    size_t base = (size_t)(o0 + ol) * D_ + k0 + kq * 16;
    *(int4*)&Mt_hi[base]     = *(int4*)&th[0];
    *(int4*)&Mt_hi[base + 8] = *(int4*)&th[8];
    *(int4*)&Mt_lo[base]     = *(int4*)&tl[0];
    *(int4*)&Mt_lo[base + 8] = *(int4*)&tl[8];
}

// ------ barrier: sc1-store protocol (verified round 8) ------
__device__ inline void gbar(unsigned* __restrict__ fl, int w, unsigned bar) {
    __syncthreads();
    asm volatile("s_waitcnt vmcnt(0)" ::: "memory");
    if (threadIdx.x == 0)
        __hip_atomic_store(&fl[w], bar, __ATOMIC_RELAXED, __HIP_MEMORY_SCOPE_AGENT);
    if (threadIdx.x < NWG) {
        while (__hip_atomic_load(&fl[threadIdx.x], __ATOMIC_RELAXED,
                                 __HIP_MEMORY_SCOPE_AGENT) < bar)
            __builtin_amdgcn_s_sleep(2);
    }
    __syncthreads();
    __builtin_amdgcn_fence(__ATOMIC_ACQUIRE, "agent");
}

// ================= 4-layer wavefront pipeline (3-phase slots) =================
// 96 WGs; WG w owns cols [16w,16w+16). wave wv owns rows [16wv,16wv+16).
// slot s: layer l does step t = s-2l. Phases: matvec -> reduce -> gate.
__global__ __launch_bounds__(256, 1) void k_pipe(
        const float* __restrict__ x,
        const ushort* __restrict__ Xbh, const ushort* __restrict__ Xbl,
        ushort* __restrict__ Xrh, ushort* __restrict__ Xrl,
        ushort* __restrict__ Hbh, ushort* __restrict__ Hbl,
        float* __restrict__ Y1, float* __restrict__ Y2,
        float* __restrict__ pstats, float* __restrict__ finals,
        unsigned* __restrict__ flags,
        const ushort* __restrict__ Uth, const ushort* __restrict__ Utl,
        const ushort* __restrict__ Wth, const ushort* __restrict__ Wtl,
        const float* __restrict__ gam, const float* __restrict__ bet,
        const float* __restrict__ bias,
        const int* __restrict__ mcode, float* __restrict__ out) {
    __shared__ __hip_bfloat16 lds[4 * 16 * 1024];   // [U_hi|U_lo|W_hi|W_lo] 32KB each
    const int w = blockIdx.x;
    const int tid = threadIdx.x;
    const int lane = tid & 63;
    const int wv = tid >> 6;
    const int lr = lane & 15;
    const int lg = lane >> 4;
    const int c0 = w * 16;
    const int b0 = wv * 16;

    // stage U/W tiles (cols c0..c0+16) into LDS, XOR-swizzled
    {
        int cl = tid >> 4, kc = tid & 15;
        const ushort* srcs0 = Uth + (size_t)(c0 + cl) * D_ + kc * 64;
        const ushort* srcs1 = Utl + (size_t)(c0 + cl) * D_ + kc * 64;
        const ushort* srcs2 = Wth + (size_t)(c0 + cl) * D_ + kc * 64;
        const ushort* srcs3 = Wtl + (size_t)(c0 + cl) * D_ + kc * 64;
        char* base = (char*)lds;
#pragma unroll
        for (int j = 0; j < 8; ++j) {
            int k = kc * 64 + j * 8;
            int off = (cl * 2048 + k * 2) ^ ((cl & 7) << 4);
            *(int4*)(base + off)           = *(const int4*)(srcs0 + j * 8);
            *(int4*)(base + 32768 + off)   = *(const int4*)(srcs1 + j * 8);
            *(int4*)(base + 65536 + off)   = *(const int4*)(srcs2 + j * 8);
            *(int4*)(base + 98304 + off)   = *(const int4*)(srcs3 + j * 8);
        }
    }
    __syncthreads();

    const int d = c0 + lr;
    const bool gate_w = (w < 64);
    const bool tanh_w = (w >= 32 && w < 64);
    float g0d = 0.f, g1d = 0.f, cd = 0.f, g0e = 0.f, g1e = 0.f, ce = 0.f;
    if (gate_w) {
        g0d = gam[d]; g1d = gam[O_ + d];
        cd  = bet[d] + bet[O_ + d] + bias[d];
    }
    if (tanh_w) {
        int e = d + 512;
        g0e = gam[e]; g1e = gam[O_ + e];
        ce  = bet[e] + bet[O_ + e] + bias[e];
    }
    int brow[4];
#pragma unroll
    for (int j = 0; j < 4; ++j) brow[j] = b0 + lg * 4 + j;

    // per-layer per-row register state (gate waves)
    float h1r[4][4] = {}, fk1r[4][4] = {};
    float oh_d1[4][4] = {}, oh_d2[4][4] = {}, fkp_d1[4][4] = {};
    f32x4 acc1[4], acc2[4];

    unsigned bar = 0;
    for (int s = 0; s < NSLOT; ++s) {
        // ---------------- phase A: matvecs + partial stats ----------------
#pragma unroll
        for (int l = 0; l < 4; ++l) {
            int t = s - 2 * l;
            bool act = (t >= 0) && (t < T_);
            if (!act) continue;
            const ushort* xsh;
            const ushort* xsl;
            if (l == 0) {
                xsh = Xbh + ((size_t)t * B_ + b0 + lr) * D_;
                xsl = Xbl + ((size_t)t * B_ + b0 + lr) * D_;
            } else {
                size_t rb = (((size_t)l * 3 + (t % 3)) * B_ + b0 + lr) * D_;
                xsh = Xrh + rb;
                xsl = Xrl + rb;
            }
            const ushort* hsh = Hbh + ((size_t)l * B_ + b0 + lr) * D_;
            const ushort* hsl = Hbl + ((size_t)l * B_ + b0 + lr) * D_;
            const char* lb = (const char*)lds;
            f32x4 a10 = {0,0,0,0}, a11 = {0,0,0,0}, a12 = {0,0,0,0};
            f32x4 a20 = {0,0,0,0}, a21 = {0,0,0,0}, a22 = {0,0,0,0};
#pragma unroll 8
            for (int kc = 0; kc < 32; ++kc) {
                int k = kc * 32 + lg * 8;
                int off = (lr * 2048 + k * 2) ^ ((lr & 7) << 4);
                bf16x8 xah = *(const bf16x8*)(xsh + k);
                bf16x8 xal = *(const bf16x8*)(xsl + k);
                bf16x8 hah = *(const bf16x8*)(hsh + k);
                bf16x8 hal = *(const bf16x8*)(hsl + k);
                bf16x8 ubh = *(const bf16x8*)(lb + off);
                bf16x8 ubl = *(const bf16x8*)(lb + 32768 + off);
                bf16x8 wbh = *(const bf16x8*)(lb + 65536 + off);
                bf16x8 wbl = *(const bf16x8*)(lb + 98304 + off);
                a10 = __builtin_amdgcn_mfma_f32_16x16x32_bf16(xah, wbh, a10, 0, 0, 0);
                a11 = __builtin_amdgcn_mfma_f32_16x16x32_bf16(xah, wbl, a11, 0, 0, 0);
                a12 = __builtin_amdgcn_mfma_f32_16x16x32_bf16(xal, wbh, a12, 0, 0, 0);
                a20 = __builtin_amdgcn_mfma_f32_16x16x32_bf16(hah, ubh, a20, 0, 0, 0);
                a21 = __builtin_amdgcn_mfma_f32_16x16x32_bf16(hah, ubl, a21, 0, 0, 0);
                a22 = __builtin_amdgcn_mfma_f32_16x16x32_bf16(hal, ubh, a22, 0, 0, 0);
            }
            acc1[l] = a10 + a11 + a12;
            acc2[l] = a20 + a21 + a22;
            // per-row partial stats -> pstats[(l,b,w)] (no contention)
#pragma unroll
            for (int j = 0; j < 4; ++j) {
                float s1 = acc1[l][j], q1 = s1 * s1;
                float s2 = acc2[l][j], q2 = s2 * s2;
#pragma unroll
                for (int m = 1; m < 16; m <<= 1) {
                    s1 += __shfl_xor(s1, m); q1 += __shfl_xor(q1, m);
                    s2 += __shfl_xor(s2, m); q2 += __shfl_xor(q2, m);
                }
                if (lr == 0) {
                    float* sp = &pstats[(((size_t)l * 64 + brow[j]) * NWG + w) * 4];
                    st_f32x2_coh(sp, s1, q1);
                    st_f32x2_coh(sp + 2, s2, q2);
                }
            }
            // export tanh-partner cols (w>=64)
            if (w >= 64) {
                int cexp = c0 + lr - 1024;
#pragma unroll
                for (int j = 0; j < 4; ++j) {
                    st_f32_coh(&Y1[((size_t)l * B_ + brow[j]) * 512 + cexp], acc1[l][j]);
                    st_f32_coh(&Y2[((size_t)l * B_ + brow[j]) * 512 + cexp], acc2[l][j]);
                }
            }
        }
        gbar(flags, w, ++bar);

        // ---------------- phase B: stats reduce (pair = w + 96*wv) ----------------
        {
            int pair = w + NWG * wv;
            if (pair < 256) {
                const float* pp = &pstats[(size_t)pair * NWG * 4];
                float s1 = 0.f, q1 = 0.f, s2 = 0.f, q2 = 0.f;
                if (lane < 32) {
#pragma unroll
                    for (int i = 0; i < 3; ++i) {
                        float4 v = *(const float4*)(pp + (lane + i * 32) * 4);
                        s1 += v.x; q1 += v.y; s2 += v.z; q2 += v.w;
                    }
                }
#pragma unroll
                for (int m = 1; m < 32; m <<= 1) {
                    s1 += __shfl_xor(s1, m); q1 += __shfl_xor(q1, m);
                    s2 += __shfl_xor(s2, m); q2 += __shfl_xor(q2, m);
                }
                if (lane == 0) {
                    float m1 = s1 * (1.f / O_);
                    float v1 = q1 * (1.f / O_) - m1 * m1;
                    float i1 = 1.f / (sqrtf(v1 + EPSf) + EPSf);
                    float m2 = s2 * (1.f / O_);
                    float v2 = q2 * (1.f / O_) - m2 * m2;
                    float i2 = 1.f / (sqrtf(v2 + EPSf) + EPSf);
                    st_f32x2_coh(&finals[(size_t)pair * 4], m1, i1);
                    st_f32x2_coh(&finals[(size_t)pair * 4 + 2], m2, i2);
                }
            }
        }
        gbar(flags, w, ++bar);

        // ---------------- phase C: gating (descending layers) ----------------
        if (gate_w) {
#pragma unroll
            for (int li = 0; li < 4; ++li) {
                const int l = 3 - li;
                const int lp = (l > 0) ? l - 1 : 0;
                int t = s - 2 * l;
                bool act = (t >= 0) && (t < T_);
                float ohn[4], ofkn[4];
                if (act) {
                    int4 mc4 = *(const int4*)&mcode[t * B_ + b0 + lg * 4];
                    int mcarr[4] = {mc4.x, mc4.y, mc4.z, mc4.w};
#pragma unroll
                    for (int j = 0; j < 4; ++j) {
                        int b = brow[j];
                        float4 sv = *(const float4*)&finals[((size_t)l * 64 + b) * 4];
                        float m1 = sv.x, i1 = sv.y, m2 = sv.z, i2 = sv.w;
                        float y1 = acc1[l][j], y2 = acc2[l][j];
                        float td = g0d * (y1 - m1) * i1 + g1d * (y2 - m2) * i2 + cd;
                        float fkc = fminf(fmaxf(0.2f * td + 0.5f, 0.f), 1.f);
                        float hpad = 0.f;
                        if (tanh_w) {
                            float y1e = Y1[((size_t)l * B_ + b) * 512 + (d - 512)];
                            float y2e = Y2[((size_t)l * B_ + b) * 512 + (d - 512)];
                            float te = g0e * (y1e - m1) * i1 + g1e * (y2e - m2) * i2 + ce;
                            hpad = tanhf(te);
                        }
                        float xt;
                        if (l == 0)
                            xt = (d < 512) ? x[((size_t)b * T_ + t) * 512 + d] : 0.f;
                        else
                            xt = oh_d2[lp][j];
                        float fkp = (l > 0 && t + 1 < T_) ? fkp_d1[lp][j] : 0.f;
                        float hc = (1.f - fkc) * xt + fkc * hpad;
                        float h  = fkp * h1r[l][j] + (1.f - fkp) * hc;
                        float fk = fkp + (1.f - fkp) * fkc;
                        int mt = mcarr[j] & 1, mn = (mcarr[j] >> 1) & 1;
                        if (mt && !mn) fk = 0.f;
                        float oh  = mt ? h  : h1r[l][j];
                        float ofk = mt ? fk : fk1r[l][j];
                        h1r[l][j] = oh; fk1r[l][j] = ofk;
                        ushort hi, lo;
                        SPLIT1(oh, hi, lo);
                        st_u16_coh(Hbh + ((size_t)l * B_ + b) * D_ + d, hi);
                        st_u16_coh(Hbl + ((size_t)l * B_ + b) * D_ + d, lo);
                        if (l < 3) {
                            size_t xb = (((size_t)(l + 1) * 3 + (t % 3)) * B_ + b) * D_ + d;
                            st_u16_coh(Xrh + xb, hi);
                            st_u16_coh(Xrl + xb, lo);
                        }
                        if (l == 3 && t == T_ - 1 && d >= 512)
                            out[(size_t)b * 512 + (d - 512)] = oh;
                        ohn[j] = oh; ofkn[j] = ofk;
                    }
                }
#pragma unroll
                for (int j = 0; j < 4; ++j) {
                    oh_d2[l][j] = oh_d1[l][j];
                    if (act) { oh_d1[l][j] = ohn[j]; fkp_d1[l][j] = ofkn[j]; }
                }
            }
        }
        gbar(flags, w, ++bar);
    }
}

extern "C" void kernel_launch(void* const* d_in, const int* in_sizes, int n_in,
                              void* d_out, int out_size, void* d_ws, size_t ws_size,
                              hipStream_t stream) {
    (void)in_sizes; (void)n_in; (void)out_size;
    const float* x      = (const float*)d_in[0];
    const int*   mask   = (const int*)d_in[1];
    const float* W      = (const float*)d_in[2];
    const float* U      = (const float*)d_in[3];
    const float* bias   = (const float*)d_in[4];
    const float* gammas = (const float*)d_in[5];
    const float* betas  = (const float*)d_in[6];

    float* ws = (float*)d_ws;
    float* Y1    = ws;                                   // 4*B_*512
    float* Y2    = Y1 + (size_t)4 * B_ * 512;            // 4*B_*512
    float* pstats = Y2 + (size_t)4 * B_ * 512;           // 4*64*96*4
    float* finals = pstats + (size_t)4 * 64 * NWG * 4;   // 256*4
    unsigned* flags = (unsigned*)(finals + 256 * 4);     // 128
    int* mcode = (int*)(flags + 128);                    // TB_
    ushort* Xbh = (ushort*)(mcode + TB_);                // TB_*D_
    ushort* Xbl = Xbh + (size_t)TB_ * D_;                // TB_*D_
    ushort* Xrh = Xbl + (size_t)TB_ * D_;                // 4*3*B_*D_
    ushort* Xrl = Xrh + (size_t)4 * 3 * B_ * D_;
    ushort* Hbh = Xrl + (size_t)4 * 3 * B_ * D_;         // 4*B_*D_
    ushort* Hbl = Hbh + (size_t)4 * B_ * D_;             // 4*B_*D_
    ushort* Uth = Hbl + (size_t)4 * B_ * D_;             // O_*D_
    ushort* Utl = Uth + (size_t)O_ * D_;
    ushort* Wth = Utl + (size_t)O_ * D_;
    ushort* Wtl = Wth + (size_t)O_ * D_;
    size_t need_bytes = ((char*)(Wtl + (size_t)O_ * D_)) - ((char*)d_ws);
    if (ws_size < need_bytes) return;

    k_prepx<<<TB_ * D_ / 4 / 256, 256, 0, stream>>>(x, Xbh, Xbl);
    k_mask<<<TB_ / 256, 256, 0, stream>>>(mask, mcode);
    k_prep<<<dim3(O_ / 64, D_ / 64), 256, 0, stream>>>(U, Uth, Utl);
    k_prep<<<dim3(O_ / 64, D_ / 64), 256, 0, stream>>>(W, Wth, Wtl);
    (void)hipMemsetAsync(Hbh, 0, sizeof(ushort) * (size_t)4 * B_ * D_ * 2, stream);
    (void)hipMemsetAsync(pstats, 0, sizeof(float) * (size_t)4 * 64 * NWG * 4, stream);
    (void)hipMemsetAsync(flags, 0, sizeof(unsigned) * 128, stream);

    k_pipe<<<NWG, 256, 0, stream>>>(x, Xbh, Xbl, Xrh, Xrl, Hbh, Hbl,
                                    Y1, Y2, pstats, finals, flags,
                                    Uth, Utl, Wth, Wtl,
                                    gammas, betas, bias, mcode, (float*)d_out);
}